// Round 11
// baseline (471.379 us; speedup 1.0000x reference)
//
#include <hip/hip_runtime.h>
#include <math.h>
#include <float.h>

#define IN_DIM   1024
#define OUT_DIM  128
#define MEM_LEN  131072
#define DIST_BLOCKS 2048   // 64 rows per block (16 rows/wave * 4 waves)

#define NA_FLOATS  ((long long)MEM_LEN * OUT_DIM)   // 16,777,216
#define NB_FLOATS  ((long long)MEM_LEN * IN_DIM)    // 134,217,728
#define N_TOTAL    (NA_FLOATS + NB_FLOATS)          // 150,994,944

// insert (v,i) into ascending-(v,i) top-3; lexicographic tie-break matches
// jax.lax.top_k stability (lower index wins on equal distance)
__device__ __forceinline__ void ins3(float v, int i,
    float& v0, int& i0, float& v1, int& i1, float& v2, int& i2) {
  if (v < v0 || (v == v0 && i < i0)) {
    v2 = v1; i2 = i1; v1 = v0; i1 = i0; v0 = v; i0 = i;
  } else if (v < v1 || (v == v1 && i < i1)) {
    v2 = v1; i2 = i1; v1 = v; i1 = i;
  } else if (v < v2 || (v == v2 && i < i2)) {
    v2 = v; i2 = i;
  }
}

// K1a: encoder GEMV, one block per output. enc[o] = tanh(new . W_enc[:,o] + b)
__global__ __launch_bounds__(256) void k1a_enc(
    const float* __restrict__ x, const float* __restrict__ mean,
    const float* __restrict__ stdv, const float* __restrict__ W_enc,
    const float* __restrict__ b_enc, float* __restrict__ ws_enc) {
  const int o = blockIdx.x;      // 0..127
  const int t = threadIdx.x;     // 0..255
  float partial = 0.0f;
  #pragma unroll
  for (int j = 0; j < 4; ++j) {
    const int k = t + 256 * j;
    const float sd = stdv[k];
    const float nv = (sd == 0.0f) ? 0.0f : (x[k] - mean[k]) / sd;
    partial += nv * W_enc[k * OUT_DIM + o];
  }
  for (int off = 32; off; off >>= 1) partial += __shfl_xor(partial, off, 64);
  __shared__ float s[4];
  if ((t & 63) == 0) s[t >> 6] = partial;
  __syncthreads();
  if (t == 0) ws_enc[o] = tanhf(s[0] + s[1] + s[2] + s[3] + b_enc[o]);
}

// K1b: decoder + squared-error partials. 8 blocks x 128 threads; block b
// handles outputs [128b, 128b+128). ws_sse[b] = sum of (rec-new)^2 there.
__global__ __launch_bounds__(128) void k1b_dec(
    const float* __restrict__ x, const float* __restrict__ mean,
    const float* __restrict__ stdv, const float* __restrict__ W_dec,
    const float* __restrict__ b_dec, const float* __restrict__ ws_enc,
    float* __restrict__ ws_sse) {
  const int t = threadIdx.x;
  const int o = blockIdx.x * 128 + t;
  __shared__ float s_enc[OUT_DIM];
  s_enc[t] = ws_enc[t];
  __syncthreads();
  float r = b_dec[o];
  #pragma unroll 8
  for (int k = 0; k < OUT_DIM; ++k) r += s_enc[k] * W_dec[k * IN_DIM + o];
  const float sd = stdv[o];
  const float nv = (sd == 0.0f) ? 0.0f : (x[o] - mean[o]) / sd;
  const float diff = r - nv;
  float sq = diff * diff;
  for (int off = 32; off; off >>= 1) sq += __shfl_xor(sq, off, 64);
  __shared__ float sr[2];
  if ((t & 63) == 0) sr[t >> 6] = sq;
  __syncthreads();
  if (t == 0) ws_sse[blockIdx.x] = sr[0] + sr[1];
}

// K2: L1 distances. float4 loads (2 rows per wave-instruction, 1KB contig),
// 5-level shfl reduce within each 32-lane half, 16 rows per wave.
// Side effect: warms `memory` (64MB) into L3 for the first copy kernel.
__global__ __launch_bounds__(256) void k2_dist(
    const float* __restrict__ memory, const float* __restrict__ ws_enc,
    float* __restrict__ topv, int* __restrict__ topi) {
  const int t = threadIdx.x;
  const int lane = t & 63;
  const int wid = t >> 6;
  const int half = lane >> 5;
  const int col  = lane & 31;
  const float4 e = reinterpret_cast<const float4*>(ws_enc)[col];
  const float4* m4 = reinterpret_cast<const float4*>(memory);
  float v0 = FLT_MAX, v1 = FLT_MAX, v2 = FLT_MAX;
  int i0 = 0x7fffffff, i1 = 0x7fffffff, i2 = 0x7fffffff;
  const int r0 = (blockIdx.x * 4 + wid) * 16;
  for (int rr = 0; rr < 16; rr += 2) {
    const float4 m = m4[(size_t)(r0 + rr) * 32 + lane];
    float d = fabsf(m.x - e.x) + fabsf(m.y - e.y)
            + fabsf(m.z - e.z) + fabsf(m.w - e.w);
    d += __shfl_xor(d, 1, 64);
    d += __shfl_xor(d, 2, 64);
    d += __shfl_xor(d, 4, 64);
    d += __shfl_xor(d, 8, 64);
    d += __shfl_xor(d, 16, 64);
    ins3(d, r0 + rr + half, v0, i0, v1, i1, v2, i2);
  }
  {
    const float w0 = __shfl_xor(v0, 32, 64);
    const float w1 = __shfl_xor(v1, 32, 64);
    const float w2 = __shfl_xor(v2, 32, 64);
    const int j0 = __shfl_xor(i0, 32, 64);
    const int j1 = __shfl_xor(i1, 32, 64);
    const int j2 = __shfl_xor(i2, 32, 64);
    ins3(w0, j0, v0, i0, v1, i1, v2, i2);
    ins3(w1, j1, v0, i0, v1, i1, v2, i2);
    ins3(w2, j2, v0, i0, v1, i1, v2, i2);
  }
  __shared__ float sv[4][3];
  __shared__ int   si[4][3];
  if (lane == 0) {
    sv[wid][0] = v0; sv[wid][1] = v1; sv[wid][2] = v2;
    si[wid][0] = i0; si[wid][1] = i1; si[wid][2] = i2;
  }
  __syncthreads();
  if (t == 0) {
    for (int w = 1; w < 4; ++w)
      for (int j = 0; j < 3; ++j)
        ins3(sv[w][j], si[w][j], v0, i0, v1, i1, v2, i2);
    topv[blockIdx.x * 3 + 0] = v0; topi[blockIdx.x * 3 + 0] = i0;
    topv[blockIdx.x * 3 + 1] = v1; topi[blockIdx.x * 3 + 1] = i1;
    topv[blockIdx.x * 3 + 2] = v2; topi[blockIdx.x * 3 + 2] = i2;
  }
}

// Scalar-dword copy, fill-kernel pattern: dst[j] = src[j] with dst only
// 4B-aligned. Contiguous dword per lane (256B = 2 full lines per wave
// instruction), zero cross-lane ops, zero edge cases. Compile-time grid/
// trip counts -> fully unrolled 8-deep independent loads. Line-request
// count identical to a float4 copy; we are ~8x memory-bound so the 4x
// instruction count is free. NT loads/stores keep the 1.2GB streams from
// churning L3.
template<int ITERS, int GRID, bool NTLOAD>
__global__ __launch_bounds__(256) void copy_dw(
    const float* __restrict__ src, float* __restrict__ dst) {
  const int tid = blockIdx.x * 256 + threadIdx.x;
  const long long GS = (long long)GRID * 256;
  #pragma unroll
  for (int it = 0; it < ITERS; ++it) {
    const long long b = (long long)it * 8 * GS + tid;
    float v[8];
    #pragma unroll
    for (int u = 0; u < 8; ++u) {
      const float* p = src + b + u * GS;
      v[u] = NTLOAD ? __builtin_nontemporal_load(p) : *p;
    }
    #pragma unroll
    for (int u = 0; u < 8; ++u)
      __builtin_nontemporal_store(v[u], dst + b + u * GS);
  }
}

// K3: mse/winloss from partials, merge candidates, final loss, conditional
// FIFO row update.
__global__ __launch_bounds__(1024) void k3_topk_update(
    const float* __restrict__ topv, const int* __restrict__ topi,
    const float* __restrict__ ws_sse, const float* __restrict__ win_mean,
    const float* __restrict__ win_std, const float* __restrict__ ws_enc,
    const float* __restrict__ x, float* __restrict__ out_loss,
    float* __restrict__ out_mem, float* __restrict__ out_md) {
  const int t = threadIdx.x;
  const int n = DIST_BLOCKS * 3;   // 6144
  float v0 = FLT_MAX, v1 = FLT_MAX, v2 = FLT_MAX;
  int i0 = 0x7fffffff, i1 = 0x7fffffff, i2 = 0x7fffffff;
  for (int j = t; j < n; j += 1024) ins3(topv[j], topi[j], v0, i0, v1, i1, v2, i2);
  for (int off = 32; off; off >>= 1) {
    const float ov0 = __shfl_xor(v0, off, 64);
    const float ov1 = __shfl_xor(v1, off, 64);
    const float ov2 = __shfl_xor(v2, off, 64);
    const int oi0 = __shfl_xor(i0, off, 64);
    const int oi1 = __shfl_xor(i1, off, 64);
    const int oi2 = __shfl_xor(i2, off, 64);
    ins3(ov0, oi0, v0, i0, v1, i1, v2, i2);
    ins3(ov1, oi1, v0, i0, v1, i1, v2, i2);
    ins3(ov2, oi2, v0, i0, v1, i1, v2, i2);
  }
  __shared__ float sv[16][3];
  __shared__ int   si[16][3];
  __shared__ int s_i0, s_cond;
  const int lane = t & 63, wid = t >> 6;
  if (lane == 0) {
    sv[wid][0] = v0; sv[wid][1] = v1; sv[wid][2] = v2;
    si[wid][0] = i0; si[wid][1] = i1; si[wid][2] = i2;
  }
  __syncthreads();
  if (t == 0) {
    for (int w = 1; w < 16; ++w)
      for (int j = 0; j < 3; ++j)
        ins3(sv[w][j], si[w][j], v0, i0, v1, i1, v2, i2);
    float sse = 0.0f;
    #pragma unroll
    for (int b = 0; b < 8; ++b) sse += ws_sse[b];
    const float mse = sse / (float)IN_DIM;
    const float z = (mse - win_mean[0]) / win_std[0];
    const float prob = 0.5f * erfcf(-z * 0.70710678118654752440f); // ndtr
    const float wl = (1.0f - prob) * mse;  // SKIP_THRESHOLD == 1
    const float loss_values = (v0 + 0.5f * v1 + 0.25f * v2) / 1.75f;
    out_loss[0] = wl + loss_values;
    s_i0 = i0;
    s_cond = (loss_values <= wl) ? 1 : 0;
  }
  __syncthreads();
  if (s_cond) {
    if (t < OUT_DIM) out_mem[(size_t)s_i0 * OUT_DIM + t] = ws_enc[t];
    out_md[(size_t)s_i0 * IN_DIM + t] = x[t];
  }
}

extern "C" void kernel_launch(void* const* d_in, const int* in_sizes, int n_in,
                              void* d_out, int out_size, void* d_ws, size_t ws_size,
                              hipStream_t stream) {
  const float* x        = (const float*)d_in[0];
  const float* mean     = (const float*)d_in[1];
  const float* stdv     = (const float*)d_in[2];
  const float* memory   = (const float*)d_in[3];
  const float* mem_data = (const float*)d_in[4];
  const float* W_enc    = (const float*)d_in[5];
  const float* b_enc    = (const float*)d_in[6];
  const float* W_dec    = (const float*)d_in[7];
  const float* b_dec    = (const float*)d_in[8];
  const float* win_mean = (const float*)d_in[9];
  const float* win_std  = (const float*)d_in[10];

  float* out      = (float*)d_out;
  float* out_loss = out;
  float* out_mem  = out + 1;
  float* out_md   = out + 1 + (size_t)MEM_LEN * OUT_DIM;

  float* ws        = (float*)d_ws;
  float* ws_enc    = ws;                     // 128
  float* ws_sse    = ws + 128;               // 8
  float* ws_topv   = ws + 256;               // 6144
  int*   ws_topi   = (int*)(ws + 256 + DIST_BLOCKS * 3);   // 6144

  k1a_enc<<<OUT_DIM, 256, 0, stream>>>(x, mean, stdv, W_enc, b_enc, ws_enc);
  k2_dist<<<DIST_BLOCKS, 256, 0, stream>>>(memory, ws_enc, ws_topv, ws_topi);
  k1b_dec<<<8, 128, 0, stream>>>(x, mean, stdv, W_dec, b_dec, ws_enc, ws_sse);
  // NA = 16,777,216 = 1024*256 * (8*8);  NB = 134,217,728 = 1024*256 * (64*8)
  copy_dw<8, 1024, false><<<1024, 256, 0, stream>>>(memory, out_mem);
  copy_dw<64, 1024, true><<<1024, 256, 0, stream>>>(mem_data, out_md);
  k3_topk_update<<<1, 1024, 0, stream>>>(ws_topv, ws_topi, ws_sse, win_mean,
                                         win_std, ws_enc, x,
                                         out_loss, out_mem, out_md);
}

// Round 12
// 308.122 us; speedup vs baseline: 1.5298x; 1.5298x over previous
//
#include <hip/hip_runtime.h>
#include <math.h>
#include <float.h>

#define IN_DIM   1024
#define OUT_DIM  128
#define MEM_LEN  131072
#define GRID_F   1024      // fused kernel: 1024 blocks * 4 waves = 4096 waves
#define CAND_BLOCKS 1024   // candidate top3 sets produced by fused kernel

#define NA_FLOATS  ((long long)MEM_LEN * OUT_DIM)   // 16,777,216
#define NB_FLOATS  ((long long)MEM_LEN * IN_DIM)    // 134,217,728
#define N_TOTAL    (NA_FLOATS + NB_FLOATS)          // 150,994,944
#define NFRAMES    (N_TOTAL / 1024)                 // 147,456 4KB output frames
#define NPAIRS     (NFRAMES / 2)                    // 73,728 (18 per wave)
#define FRAME_MEM  16384                            // frames < this source from memory
#define NPAIRS_MEM 8192                             // pairs fully in memory region

// insert (v,i) into ascending-(v,i) top-3; lexicographic tie-break matches
// jax.lax.top_k stability (lower index wins on equal distance)
__device__ __forceinline__ void ins3(float v, int i,
    float& v0, int& i0, float& v1, int& i1, float& v2, int& i2) {
  if (v < v0 || (v == v0 && i < i0)) {
    v2 = v1; i2 = i1; v1 = v0; i1 = i0; v0 = v; i0 = i;
  } else if (v < v1 || (v == v1 && i < i1)) {
    v2 = v1; i2 = i1; v1 = v; i1 = i;
  } else if (v < v2 || (v == v2 && i < i2)) {
    v2 = v; i2 = i;
  }
}

// K1a: encoder GEMV, one block per output. enc[o] = tanh(new . W_enc[:,o] + b)
__global__ __launch_bounds__(256) void k1a_enc(
    const float* __restrict__ x, const float* __restrict__ mean,
    const float* __restrict__ stdv, const float* __restrict__ W_enc,
    const float* __restrict__ b_enc, float* __restrict__ ws_enc) {
  const int o = blockIdx.x;      // 0..127
  const int t = threadIdx.x;     // 0..255
  float partial = 0.0f;
  #pragma unroll
  for (int j = 0; j < 4; ++j) {
    const int k = t + 256 * j;
    const float sd = stdv[k];
    const float nv = (sd == 0.0f) ? 0.0f : (x[k] - mean[k]) / sd;
    partial += nv * W_enc[k * OUT_DIM + o];
  }
  for (int off = 32; off; off >>= 1) partial += __shfl_xor(partial, off, 64);
  __shared__ float s[4];
  if ((t & 63) == 0) s[t >> 6] = partial;
  __syncthreads();
  if (t == 0) ws_enc[o] = tanhf(s[0] + s[1] + s[2] + s[3] + b_enc[o]);
}

// K1b: decoder + squared-error partials. 8 blocks x 128 threads.
__global__ __launch_bounds__(128) void k1b_dec(
    const float* __restrict__ x, const float* __restrict__ mean,
    const float* __restrict__ stdv, const float* __restrict__ W_dec,
    const float* __restrict__ b_dec, const float* __restrict__ ws_enc,
    float* __restrict__ ws_sse) {
  const int t = threadIdx.x;
  const int o = blockIdx.x * 128 + t;
  __shared__ float s_enc[OUT_DIM];
  s_enc[t] = ws_enc[t];
  __syncthreads();
  float r = b_dec[o];
  #pragma unroll 8
  for (int k = 0; k < OUT_DIM; ++k) r += s_enc[k] * W_dec[k * IN_DIM + o];
  const float sd = stdv[o];
  const float nv = (sd == 0.0f) ? 0.0f : (x[o] - mean[o]) / sd;
  const float diff = r - nv;
  float sq = diff * diff;
  for (int off = 32; off; off >>= 1) sq += __shfl_xor(sq, off, 64);
  __shared__ float sr[2];
  if ((t & 63) == 0) sr[t >> 6] = sq;
  __syncthreads();
  if (t == 0) ws_sse[blockIdx.x] = sr[0] + sr[1];
}

// Fused realigned copy + L1 distance. Wave handles a PAIR of consecutive
// 4KB frames per iteration: 8 aligned 1KB float4 loads (+1 edge dword) ->
// [if memory region: 8x (4 fabs + 5 shfl_xor) distance reduce on the RAW
// values, 2 rows per quad] -> 15 shfl realign -> 8 aligned full-line plain
// stores. memory is read exactly ONCE for the whole problem. Per-block
// top3 candidates -> topv/topi[blockIdx].
__global__ __launch_bounds__(256) void fused_copy_dist(
    const float* __restrict__ memory, const float* __restrict__ mem_data,
    const float* __restrict__ ws_enc, float* __restrict__ out,
    float* __restrict__ topv, int* __restrict__ topi) {
  const int t = threadIdx.x;
  const int lane = t & 63;
  const int wid  = t >> 6;
  const float4* mem4 = reinterpret_cast<const float4*>(memory);
  const float4* md4  = reinterpret_cast<const float4*>(mem_data);
  float4* out4 = reinterpret_cast<float4*>(out);
  const float4 e = reinterpret_cast<const float4*>(ws_enc)[lane & 31];
  float v0 = FLT_MAX, v1 = FLT_MAX, v2 = FLT_MAX;
  int i0 = 0x7fffffff, i1 = 0x7fffffff, i2 = 0x7fffffff;
  const long long wstride = (long long)GRID_F * 4;
  for (long long P = (long long)blockIdx.x * 4 + wid; P < NPAIRS; P += wstride) {
    const long long sA = 2 * P;     // frames sA, sA+1 (never straddle regions)
    const float4* srcA = (sA < FRAME_MEM) ? (mem4 + (sA << 8))
                                          : (md4 + ((sA - FRAME_MEM) << 8));
    const float4* srcB = srcA + 256;
    float edge = 0.0f;
    if (P > 0) {
      const long long sd = (sA << 10) - 1;
      edge = (sd < NA_FLOATS) ? memory[sd] : mem_data[sd - NA_FLOATS];
    }
    const float4 a0 = srcA[lane];
    const float4 a1 = srcA[lane + 64];
    const float4 a2 = srcA[lane + 128];
    const float4 a3 = srcA[lane + 192];
    const float4 b0 = srcB[lane];
    const float4 b1 = srcB[lane + 64];
    const float4 b2 = srcB[lane + 128];
    const float4 b3 = srcB[lane + 192];
    if (P < NPAIRS_MEM) {
      // L1 distances on raw rows: quad Q spans rows 16P+Q (lanes<32) and
      // 16P+Q+1 (lanes>=32); 5-level xor-reduce within each 32-half.
      const int rbase = (int)(16 * P) + (lane >> 5);
#define DIST_Q(V, Q)                                                         \
      {                                                                      \
        float d = fabsf(V.x - e.x) + fabsf(V.y - e.y)                        \
                + fabsf(V.z - e.z) + fabsf(V.w - e.w);                       \
        d += __shfl_xor(d, 1, 64);                                           \
        d += __shfl_xor(d, 2, 64);                                           \
        d += __shfl_xor(d, 4, 64);                                           \
        d += __shfl_xor(d, 8, 64);                                           \
        d += __shfl_xor(d, 16, 64);                                          \
        ins3(d, rbase + (Q), v0, i0, v1, i1, v2, i2);                        \
      }
      DIST_Q(a0, 0)  DIST_Q(a1, 2)  DIST_Q(a2, 4)  DIST_Q(a3, 6)
      DIST_Q(b0, 8)  DIST_Q(b1, 10) DIST_Q(b2, 12) DIST_Q(b3, 14)
#undef DIST_Q
    }
    float p0 = __shfl_up(a0.w, 1, 64);
    float p1 = __shfl_up(a1.w, 1, 64);
    float p2 = __shfl_up(a2.w, 1, 64);
    float p3 = __shfl_up(a3.w, 1, 64);
    float q0 = __shfl_up(b0.w, 1, 64);
    float q1 = __shfl_up(b1.w, 1, 64);
    float q2 = __shfl_up(b2.w, 1, 64);
    float q3 = __shfl_up(b3.w, 1, 64);
    const float tA1 = __shfl(a0.w, 63, 64);
    const float tA2 = __shfl(a1.w, 63, 64);
    const float tA3 = __shfl(a2.w, 63, 64);
    const float tB0 = __shfl(a3.w, 63, 64);
    const float tB1 = __shfl(b0.w, 63, 64);
    const float tB2 = __shfl(b1.w, 63, 64);
    const float tB3 = __shfl(b2.w, 63, 64);
    if (lane == 0) {
      p0 = edge; p1 = tA1; p2 = tA2; p3 = tA3;
      q0 = tB0;  q1 = tB1; q2 = tB2; q3 = tB3;
    }
    float4* oA = out4 + (sA << 8);
    oA[lane]       = make_float4(p0, a0.x, a0.y, a0.z);
    oA[lane + 64]  = make_float4(p1, a1.x, a1.y, a1.z);
    oA[lane + 128] = make_float4(p2, a2.x, a2.y, a2.z);
    oA[lane + 192] = make_float4(p3, a3.x, a3.y, a3.z);
    float4* oB = oA + 256;
    oB[lane]       = make_float4(q0, b0.x, b0.y, b0.z);
    oB[lane + 64]  = make_float4(q1, b1.x, b1.y, b1.z);
    oB[lane + 128] = make_float4(q2, b2.x, b2.y, b2.z);
    oB[lane + 192] = make_float4(q3, b3.x, b3.y, b3.z);
  }
  // block-level candidate merge (4 waves)
  __shared__ float sv[4][3];
  __shared__ int   si[4][3];
  if (lane == 0) {
    sv[wid][0] = v0; sv[wid][1] = v1; sv[wid][2] = v2;
    si[wid][0] = i0; si[wid][1] = i1; si[wid][2] = i2;
  }
  __syncthreads();
  if (t == 0) {
    for (int w = 1; w < 4; ++w)
      for (int j = 0; j < 3; ++j)
        ins3(sv[w][j], si[w][j], v0, i0, v1, i1, v2, i2);
    topv[blockIdx.x * 3 + 0] = v0; topi[blockIdx.x * 3 + 0] = i0;
    topv[blockIdx.x * 3 + 1] = v1; topi[blockIdx.x * 3 + 1] = i1;
    topv[blockIdx.x * 3 + 2] = v2; topi[blockIdx.x * 3 + 2] = i2;
    if (blockIdx.x == 0) out[N_TOTAL] = mem_data[NB_FLOATS - 1];
  }
}

// K3: mse/winloss from partials, merge candidates, final loss (overwrites
// out[0] garbage), conditional FIFO row update.
__global__ __launch_bounds__(1024) void k3_topk_update(
    const float* __restrict__ topv, const int* __restrict__ topi,
    const float* __restrict__ ws_sse, const float* __restrict__ win_mean,
    const float* __restrict__ win_std, const float* __restrict__ ws_enc,
    const float* __restrict__ x, float* __restrict__ out_loss,
    float* __restrict__ out_mem, float* __restrict__ out_md) {
  const int t = threadIdx.x;
  const int n = CAND_BLOCKS * 3;   // 3072
  float v0 = FLT_MAX, v1 = FLT_MAX, v2 = FLT_MAX;
  int i0 = 0x7fffffff, i1 = 0x7fffffff, i2 = 0x7fffffff;
  for (int j = t; j < n; j += 1024) ins3(topv[j], topi[j], v0, i0, v1, i1, v2, i2);
  for (int off = 32; off; off >>= 1) {
    const float ov0 = __shfl_xor(v0, off, 64);
    const float ov1 = __shfl_xor(v1, off, 64);
    const float ov2 = __shfl_xor(v2, off, 64);
    const int oi0 = __shfl_xor(i0, off, 64);
    const int oi1 = __shfl_xor(i1, off, 64);
    const int oi2 = __shfl_xor(i2, off, 64);
    ins3(ov0, oi0, v0, i0, v1, i1, v2, i2);
    ins3(ov1, oi1, v0, i0, v1, i1, v2, i2);
    ins3(ov2, oi2, v0, i0, v1, i1, v2, i2);
  }
  __shared__ float sv[16][3];
  __shared__ int   si[16][3];
  __shared__ int s_i0, s_cond;
  const int lane = t & 63, wid = t >> 6;
  if (lane == 0) {
    sv[wid][0] = v0; sv[wid][1] = v1; sv[wid][2] = v2;
    si[wid][0] = i0; si[wid][1] = i1; si[wid][2] = i2;
  }
  __syncthreads();
  if (t == 0) {
    for (int w = 1; w < 16; ++w)
      for (int j = 0; j < 3; ++j)
        ins3(sv[w][j], si[w][j], v0, i0, v1, i1, v2, i2);
    float sse = 0.0f;
    #pragma unroll
    for (int b = 0; b < 8; ++b) sse += ws_sse[b];
    const float mse = sse / (float)IN_DIM;
    const float z = (mse - win_mean[0]) / win_std[0];
    const float prob = 0.5f * erfcf(-z * 0.70710678118654752440f); // ndtr
    const float wl = (1.0f - prob) * mse;  // SKIP_THRESHOLD == 1
    const float loss_values = (v0 + 0.5f * v1 + 0.25f * v2) / 1.75f;
    out_loss[0] = wl + loss_values;
    s_i0 = i0;
    s_cond = (loss_values <= wl) ? 1 : 0;
  }
  __syncthreads();
  if (s_cond) {
    if (t < OUT_DIM) out_mem[(size_t)s_i0 * OUT_DIM + t] = ws_enc[t];
    out_md[(size_t)s_i0 * IN_DIM + t] = x[t];
  }
}

extern "C" void kernel_launch(void* const* d_in, const int* in_sizes, int n_in,
                              void* d_out, int out_size, void* d_ws, size_t ws_size,
                              hipStream_t stream) {
  const float* x        = (const float*)d_in[0];
  const float* mean     = (const float*)d_in[1];
  const float* stdv     = (const float*)d_in[2];
  const float* memory   = (const float*)d_in[3];
  const float* mem_data = (const float*)d_in[4];
  const float* W_enc    = (const float*)d_in[5];
  const float* b_enc    = (const float*)d_in[6];
  const float* W_dec    = (const float*)d_in[7];
  const float* b_dec    = (const float*)d_in[8];
  const float* win_mean = (const float*)d_in[9];
  const float* win_std  = (const float*)d_in[10];

  float* out      = (float*)d_out;
  float* out_loss = out;
  float* out_mem  = out + 1;
  float* out_md   = out + 1 + (size_t)MEM_LEN * OUT_DIM;

  float* ws        = (float*)d_ws;
  float* ws_enc    = ws;                     // 128
  float* ws_sse    = ws + 128;               // 8
  float* ws_topv   = ws + 256;               // 3072
  int*   ws_topi   = (int*)(ws + 256 + CAND_BLOCKS * 3);   // 3072

  k1a_enc<<<OUT_DIM, 256, 0, stream>>>(x, mean, stdv, W_enc, b_enc, ws_enc);
  k1b_dec<<<8, 128, 0, stream>>>(x, mean, stdv, W_dec, b_dec, ws_enc, ws_sse);
  fused_copy_dist<<<GRID_F, 256, 0, stream>>>(memory, mem_data, ws_enc, out,
                                              ws_topv, ws_topi);
  k3_topk_update<<<1, 1024, 0, stream>>>(ws_topv, ws_topi, ws_sse, win_mean,
                                         win_std, ws_enc, x,
                                         out_loss, out_mem, out_md);
}